// Round 11
// baseline (1208.802 us; speedup 1.0000x reference)
//
#include <hip/hip_runtime.h>
#include <hip/hip_bf16.h>
#include <hip/hip_cooperative_groups.h>

namespace cg = cooperative_groups;

#define K_DIM 256
constexpr int GRIDN = 768;   // 3 blocks/CU; co-residency FORCED by __launch_bounds__(256,3)
constexpr int BLK = 256;
constexpr int SCAN_C = 512;  // cnt elements per scan block (2 per thread)

typedef __attribute__((ext_vector_type(8))) short short8;
typedef __attribute__((ext_vector_type(4))) float f32x4;

// ---------------------------------------------------------------------------
// bf16 helpers
// ---------------------------------------------------------------------------

__device__ __forceinline__ unsigned short bf16_hi(float v) {
    __hip_bfloat16 h = __float2bfloat16(v);
    return *(unsigned short*)&h;
}
__device__ __forceinline__ float bf16_back(unsigned short u) {
    __hip_bfloat16 h = *(__hip_bfloat16*)&u;
    return __bfloat162float(h);
}
__device__ __forceinline__ float bf2f(unsigned short u) {
    unsigned int b = ((unsigned int)u) << 16;
    float f;
    __builtin_memcpy(&f, &b, 4);
    return f;
}

// ---------------------------------------------------------------------------
// Fused cooperative kernel: all phases in one launch, grid.sync between.
// ---------------------------------------------------------------------------

struct Params {
    const float* x;
    const int* src;
    const int* dst;
    const float* W1;
    const float* b1;
    const float* W2;
    const float* b2;
    int N, E, nscan;
    int* cnt;
    int* row_ptr;
    int* fill;
    int* col;
    int* bsum;
    float* wnorm;
    float* dis;
    float* h;
    unsigned short* xw1;
    unsigned short* xw2;
    float* out;
};

// MFMA bf16x3 (split-fp32) GEMM phase. Tile 128x128, BK=32, 4 waves (2x2),
// grid-stride over tiles. LDS row stride 40 shorts (80B).
template <int NCOLS>
__device__ void gemm_phase(const float* __restrict__ A, const float* __restrict__ B,
                           unsigned short* __restrict__ C, int M,
                           unsigned short* lds) {
    unsigned short(*As_hi)[40] = (unsigned short(*)[40])(lds);
    unsigned short(*As_lo)[40] = (unsigned short(*)[40])(lds + 128 * 40);
    unsigned short(*Bs_hi)[40] = (unsigned short(*)[40])(lds + 2 * 128 * 40);
    unsigned short(*Bs_lo)[40] = (unsigned short(*)[40])(lds + 3 * 128 * 40);

    const int t = threadIdx.x;
    const int lane = t & 63;
    const int wid = t >> 6;
    const int wm = wid >> 1;
    const int wn = wid & 1;

    const int a_r = t >> 3;
    const int a_c4 = t & 7;
    const int b_col = t & 127;
    const int b_kq0 = t >> 7;

    const int ntn = NCOLS / 128;
    const int ntm = (M + 127) / 128;
    const int ntiles = ntm * ntn;

    for (int tile = blockIdx.x; tile < ntiles; tile += GRIDN) {
        const int m0 = (tile / ntn) * 128;
        const int n0 = (tile % ntn) * 128;

        f32x4 acc[4][4];
#pragma unroll
        for (int i = 0; i < 4; ++i)
#pragma unroll
            for (int j = 0; j < 4; ++j) acc[i][j] = (f32x4)(0.f);

        for (int k0 = 0; k0 < K_DIM; k0 += 32) {
            __syncthreads();  // previous readers done (also tile-to-tile)

#pragma unroll
            for (int p = 0; p < 4; ++p) {
                const int row = a_r + p * 32;
                const int grow = min(m0 + row, M - 1);
                const float4 v = *(const float4*)(A + (size_t)grow * K_DIM + k0 + a_c4 * 4);
                unsigned short h0 = bf16_hi(v.x), h1 = bf16_hi(v.y),
                               h2 = bf16_hi(v.z), h3 = bf16_hi(v.w);
                unsigned short l0 = bf16_hi(v.x - bf16_back(h0)),
                               l1 = bf16_hi(v.y - bf16_back(h1)),
                               l2 = bf16_hi(v.z - bf16_back(h2)),
                               l3 = bf16_hi(v.w - bf16_back(h3));
                *(ushort4*)&As_hi[row][a_c4 * 4] = make_ushort4(h0, h1, h2, h3);
                *(ushort4*)&As_lo[row][a_c4 * 4] = make_ushort4(l0, l1, l2, l3);
            }

#pragma unroll
            for (int p = 0; p < 4; ++p) {
                const int kq = b_kq0 + p * 2;
                float v0 = B[(size_t)(k0 + kq * 4 + 0) * NCOLS + n0 + b_col];
                float v1 = B[(size_t)(k0 + kq * 4 + 1) * NCOLS + n0 + b_col];
                float v2 = B[(size_t)(k0 + kq * 4 + 2) * NCOLS + n0 + b_col];
                float v3 = B[(size_t)(k0 + kq * 4 + 3) * NCOLS + n0 + b_col];
                unsigned short h0 = bf16_hi(v0), h1 = bf16_hi(v1),
                               h2 = bf16_hi(v2), h3 = bf16_hi(v3);
                unsigned short l0 = bf16_hi(v0 - bf16_back(h0)),
                               l1 = bf16_hi(v1 - bf16_back(h1)),
                               l2 = bf16_hi(v2 - bf16_back(h2)),
                               l3 = bf16_hi(v3 - bf16_back(h3));
                *(ushort4*)&Bs_hi[b_col][kq * 4] = make_ushort4(h0, h1, h2, h3);
                *(ushort4*)&Bs_lo[b_col][kq * 4] = make_ushort4(l0, l1, l2, l3);
            }

            __syncthreads();

            const int fr = lane & 15;
            const int fk = (lane >> 4) * 8;
            short8 a_hi[4], a_lo[4], b_hi[4], b_lo[4];
#pragma unroll
            for (int fm = 0; fm < 4; ++fm) {
                const int r = wm * 64 + fm * 16 + fr;
                a_hi[fm] = *(const short8*)&As_hi[r][fk];
                a_lo[fm] = *(const short8*)&As_lo[r][fk];
            }
#pragma unroll
            for (int fn = 0; fn < 4; ++fn) {
                const int c = wn * 64 + fn * 16 + fr;
                b_hi[fn] = *(const short8*)&Bs_hi[c][fk];
                b_lo[fn] = *(const short8*)&Bs_lo[c][fk];
            }

#pragma unroll
            for (int fm = 0; fm < 4; ++fm)
#pragma unroll
                for (int fn = 0; fn < 4; ++fn) {
                    acc[fm][fn] = __builtin_amdgcn_mfma_f32_16x16x32_bf16(
                        a_hi[fm], b_hi[fn], acc[fm][fn], 0, 0, 0);
                    acc[fm][fn] = __builtin_amdgcn_mfma_f32_16x16x32_bf16(
                        a_hi[fm], b_lo[fn], acc[fm][fn], 0, 0, 0);
                    acc[fm][fn] = __builtin_amdgcn_mfma_f32_16x16x32_bf16(
                        a_lo[fm], b_hi[fn], acc[fm][fn], 0, 0, 0);
                }
        }

        const int c_col = n0 + wn * 64 + (lane & 15);
        const int r_base = m0 + wm * 64 + (lane >> 4) * 4;
#pragma unroll
        for (int fm = 0; fm < 4; ++fm)
#pragma unroll
            for (int fn = 0; fn < 4; ++fn)
#pragma unroll
                for (int r = 0; r < 4; ++r) {
                    const int row = r_base + fm * 16 + r;
                    if (row < M)
                        C[(size_t)row * NCOLS + c_col + fn * 16] = bf16_hi(acc[fm][fn][r]);
                }
    }
}

// CSR aggregation over bf16 features; edge loop unrolled x4 (MLP compensation
// for the fused kernel's lower occupancy).
template <int F, bool RELU>
__device__ void agg_phase(const unsigned short* __restrict__ xw,
                          const int* __restrict__ row_ptr, const int* __restrict__ col,
                          const float* __restrict__ wnorm, const float* __restrict__ dis,
                          const float* __restrict__ bias, float* __restrict__ out, int N) {
    constexpr int VEC = F / 64;
    const int wid = threadIdx.x >> 6;
    const int lane = threadIdx.x & 63;

    for (int n = blockIdx.x * 4 + wid; n < N; n += GRIDN * 4) {
        const float dn = dis[n];
        float acc[VEC];
        {
            const float w = dn * dn;
            const unsigned short* xn = xw + (size_t)n * F + lane * VEC;
            if (VEC == 4) {
                const ushort4 u = *(const ushort4*)xn;
                acc[0] = bf2f(u.x) * w;
                acc[1] = bf2f(u.y) * w;
                acc[2] = bf2f(u.z) * w;
                acc[3] = bf2f(u.w) * w;
            } else {
                const ushort2 u = *(const ushort2*)xn;
                acc[0] = bf2f(u.x) * w;
                acc[1] = bf2f(u.y) * w;
            }
        }

        const int e0 = row_ptr[n];
        const int e1 = row_ptr[n + 1];
        int e = e0;
        for (; e + 4 <= e1; e += 4) {
            const int s0 = col[e], s1 = col[e + 1], s2 = col[e + 2], s3 = col[e + 3];
            const float w0 = wnorm[e], w1 = wnorm[e + 1], w2 = wnorm[e + 2], w3 = wnorm[e + 3];
            const unsigned short* x0 = xw + (size_t)s0 * F + lane * VEC;
            const unsigned short* x1 = xw + (size_t)s1 * F + lane * VEC;
            const unsigned short* x2 = xw + (size_t)s2 * F + lane * VEC;
            const unsigned short* x3 = xw + (size_t)s3 * F + lane * VEC;
            if (VEC == 4) {
                const ushort4 u0 = *(const ushort4*)x0;
                const ushort4 u1 = *(const ushort4*)x1;
                const ushort4 u2 = *(const ushort4*)x2;
                const ushort4 u3 = *(const ushort4*)x3;
                acc[0] += bf2f(u0.x) * w0 + bf2f(u1.x) * w1 + bf2f(u2.x) * w2 + bf2f(u3.x) * w3;
                acc[1] += bf2f(u0.y) * w0 + bf2f(u1.y) * w1 + bf2f(u2.y) * w2 + bf2f(u3.y) * w3;
                acc[2] += bf2f(u0.z) * w0 + bf2f(u1.z) * w1 + bf2f(u2.z) * w2 + bf2f(u3.z) * w3;
                acc[3] += bf2f(u0.w) * w0 + bf2f(u1.w) * w1 + bf2f(u2.w) * w2 + bf2f(u3.w) * w3;
            } else {
                const ushort2 u0 = *(const ushort2*)x0;
                const ushort2 u1 = *(const ushort2*)x1;
                const ushort2 u2 = *(const ushort2*)x2;
                const ushort2 u3 = *(const ushort2*)x3;
                acc[0] += bf2f(u0.x) * w0 + bf2f(u1.x) * w1 + bf2f(u2.x) * w2 + bf2f(u3.x) * w3;
                acc[1] += bf2f(u0.y) * w0 + bf2f(u1.y) * w1 + bf2f(u2.y) * w2 + bf2f(u3.y) * w3;
            }
        }
        for (; e < e1; ++e) {
            const int s0 = col[e];
            const float w0 = wnorm[e];
            const unsigned short* x0 = xw + (size_t)s0 * F + lane * VEC;
            if (VEC == 4) {
                const ushort4 u0 = *(const ushort4*)x0;
                acc[0] += bf2f(u0.x) * w0;
                acc[1] += bf2f(u0.y) * w0;
                acc[2] += bf2f(u0.z) * w0;
                acc[3] += bf2f(u0.w) * w0;
            } else {
                const ushort2 u0 = *(const ushort2*)x0;
                acc[0] += bf2f(u0.x) * w0;
                acc[1] += bf2f(u0.y) * w0;
            }
        }

        float* o = out + (size_t)n * F + lane * VEC;
#pragma unroll
        for (int v = 0; v < VEC; ++v) {
            float r = acc[v] + bias[lane * VEC + v];
            if (RELU) r = fmaxf(r, 0.f);
            o[v] = r;
        }
    }
}

// __launch_bounds__(256, 3): 3 waves/EU min => VGPR capped (<=170) so 3 blocks/CU
// are guaranteed allocatable (LDS 3x40KB=120 <= 160KB). GRIDN=768 = 3*256 CUs
// co-resident -> grid.sync cannot deadlock. (Round-10 failure theory: without
// the min-waves arg the compiler could exceed 170 VGPR -> 2 blocks/CU -> 512
// resident < 768 -> deadlock.)
__global__ void __launch_bounds__(256, 3) fused_kernel(Params p) {
    __shared__ unsigned short lds[4 * 128 * 40];  // 40 KiB, shared across phases
    cg::grid_group grid = cg::this_grid();
    const int t = threadIdx.x;
    const int bid = blockIdx.x;
    const int gtid = bid * BLK + t;
    const int gsize = GRIDN * BLK;
    int* sh = (int*)lds;

    // P0: zero cnt
    for (int i = gtid; i < p.N; i += gsize) p.cnt[i] = 0;
    grid.sync();

    // P1: degree histogram of dst
    for (int e = gtid; e < p.E; e += gsize) atomicAdd(&p.cnt[p.dst[e]], 1);
    grid.sync();

    // P2: scan phase1 — per-block partial sums
    if (bid < p.nscan) {
        const int i0 = bid * SCAN_C + 2 * t;
        int s = 0;
        if (i0 < p.N) s += p.cnt[i0];
        if (i0 + 1 < p.N) s += p.cnt[i0 + 1];
        sh[t] = s;
        __syncthreads();
        for (int off = 128; off > 0; off >>= 1) {
            if (t < off) sh[t] += sh[t + off];
            __syncthreads();
        }
        if (t == 0) p.bsum[bid] = sh[0];
    }
    grid.sync();

    // P3: scan phase2 — block 0 scans block sums
    if (bid == 0) {
        int v = (t < p.nscan) ? p.bsum[t] : 0;
        sh[t] = v;
        __syncthreads();
        for (int off = 1; off < 256; off <<= 1) {
            int u = (t >= off) ? sh[t - off] : 0;
            __syncthreads();
            sh[t] += u;
            __syncthreads();
        }
        if (t < p.nscan) p.bsum[t] = (t == 0) ? 0 : sh[t - 1];
        if (t == 255) p.row_ptr[p.N] = sh[255];
    }
    grid.sync();

    // P4: scan phase3 — local scan + offset; row_ptr, fill, dis
    if (bid < p.nscan) {
        const int i0 = bid * SCAN_C + 2 * t;
        const int c0 = (i0 < p.N) ? p.cnt[i0] : 0;
        const int c1 = (i0 + 1 < p.N) ? p.cnt[i0 + 1] : 0;
        sh[t] = c0 + c1;
        __syncthreads();
        for (int off = 1; off < 256; off <<= 1) {
            int u = (t >= off) ? sh[t - off] : 0;
            __syncthreads();
            sh[t] += u;
            __syncthreads();
        }
        const int excl = ((t == 0) ? 0 : sh[t - 1]) + p.bsum[bid];
        if (i0 < p.N) {
            p.row_ptr[i0] = excl;
            p.fill[i0] = excl;
            p.dis[i0] = rsqrtf((float)(c0 + 1));
        }
        if (i0 + 1 < p.N) {
            p.row_ptr[i0 + 1] = excl + c0;
            p.fill[i0 + 1] = excl + c0;
            p.dis[i0 + 1] = rsqrtf((float)(c1 + 1));
        }
    }
    grid.sync();

    // P5: CSR scatter + per-edge weights
    for (int e = gtid; e < p.E; e += gsize) {
        const int s = p.src[e];
        const int d = p.dst[e];
        const int pos = atomicAdd(&p.fill[d], 1);
        p.col[pos] = s;
        p.wnorm[pos] = p.dis[s] * p.dis[d];
    }
    grid.sync();

    // P6: layer-1 GEMM  xw1 = bf16(x @ W1)
    gemm_phase<256>(p.x, p.W1, p.xw1, p.N, lds);
    grid.sync();

    // P7: layer-1 aggregation (+bias, ReLU) -> h (fp32)
    agg_phase<256, true>(p.xw1, p.row_ptr, p.col, p.wnorm, p.dis, p.b1, p.h, p.N);
    grid.sync();

    // P8: layer-2 GEMM  xw2 = bf16(h @ W2)
    gemm_phase<128>(p.h, p.W2, p.xw2, p.N, lds);
    grid.sync();

    // P9: layer-2 aggregation (+bias) -> out (fp32)
    agg_phase<128, false>(p.xw2, p.row_ptr, p.col, p.wnorm, p.dis, p.b2, p.out, p.N);
}

// ---------------------------------------------------------------------------
// Fallback path (round-8 kernels, proven): used only if cooperative launch
// is rejected.
// ---------------------------------------------------------------------------

__global__ void degree_hist_kernel(const int* __restrict__ dst, int E,
                                   int* __restrict__ cnt) {
    int e = blockIdx.x * blockDim.x + threadIdx.x;
    if (e < E) atomicAdd(&cnt[dst[e]], 1);
}

__global__ __launch_bounds__(256) void scan_phase1(const int* __restrict__ cnt,
                                                   int* __restrict__ bsum, int N) {
    const int t = threadIdx.x;
    const int i0 = blockIdx.x * SCAN_C + 2 * t;
    int s = 0;
    if (i0 < N) s += cnt[i0];
    if (i0 + 1 < N) s += cnt[i0 + 1];
    __shared__ int sh[256];
    sh[t] = s;
    __syncthreads();
    for (int off = 128; off > 0; off >>= 1) {
        if (t < off) sh[t] += sh[t + off];
        __syncthreads();
    }
    if (t == 0) bsum[blockIdx.x] = sh[0];
}

__global__ __launch_bounds__(256) void scan_phase2(int* __restrict__ bsum, int nb,
                                                   int* __restrict__ row_ptr, int N) {
    const int t = threadIdx.x;
    int v = (t < nb) ? bsum[t] : 0;
    __shared__ int sh[256];
    sh[t] = v;
    __syncthreads();
    for (int off = 1; off < 256; off <<= 1) {
        int u = (t >= off) ? sh[t - off] : 0;
        __syncthreads();
        sh[t] += u;
        __syncthreads();
    }
    if (t < nb) bsum[t] = (t == 0) ? 0 : sh[t - 1];
    if (t == 255) row_ptr[N] = sh[255];
}

__global__ __launch_bounds__(256) void scan_phase3(const int* __restrict__ cnt,
                                                   const int* __restrict__ bsum,
                                                   int* __restrict__ row_ptr,
                                                   int* __restrict__ fill,
                                                   float* __restrict__ dis, int N) {
    const int t = threadIdx.x;
    const int i0 = blockIdx.x * SCAN_C + 2 * t;
    const int c0 = (i0 < N) ? cnt[i0] : 0;
    const int c1 = (i0 + 1 < N) ? cnt[i0 + 1] : 0;
    __shared__ int sh[256];
    sh[t] = c0 + c1;
    __syncthreads();
    for (int off = 1; off < 256; off <<= 1) {
        int u = (t >= off) ? sh[t - off] : 0;
        __syncthreads();
        sh[t] += u;
        __syncthreads();
    }
    const int excl = ((t == 0) ? 0 : sh[t - 1]) + bsum[blockIdx.x];
    if (i0 < N) {
        row_ptr[i0] = excl;
        fill[i0] = excl;
        dis[i0] = rsqrtf((float)(c0 + 1));
    }
    if (i0 + 1 < N) {
        row_ptr[i0 + 1] = excl + c0;
        fill[i0 + 1] = excl + c0;
        dis[i0 + 1] = rsqrtf((float)(c1 + 1));
    }
}

__global__ void build_csr_kernel(const int* __restrict__ src,
                                 const int* __restrict__ dst, int E,
                                 int* __restrict__ fill, int* __restrict__ col,
                                 const float* __restrict__ dis,
                                 float* __restrict__ wnorm) {
    int e = blockIdx.x * blockDim.x + threadIdx.x;
    if (e < E) {
        int s = src[e];
        int d = dst[e];
        int pos = atomicAdd(&fill[d], 1);
        col[pos] = s;
        wnorm[pos] = dis[s] * dis[d];
    }
}

template <int NCOLS>
__global__ __launch_bounds__(256) void gemm_mfma_kernel(const float* __restrict__ A,
                                                        const float* __restrict__ B,
                                                        unsigned short* __restrict__ C,
                                                        int M) {
    __shared__ unsigned short lds[4 * 128 * 40];
    const int t = threadIdx.x;
    const int ntn = NCOLS / 128;
    const int tile = blockIdx.x;
    unsigned short(*As_hi)[40] = (unsigned short(*)[40])(lds);
    unsigned short(*As_lo)[40] = (unsigned short(*)[40])(lds + 128 * 40);
    unsigned short(*Bs_hi)[40] = (unsigned short(*)[40])(lds + 2 * 128 * 40);
    unsigned short(*Bs_lo)[40] = (unsigned short(*)[40])(lds + 3 * 128 * 40);

    const int lane = t & 63;
    const int wid = t >> 6;
    const int wm = wid >> 1;
    const int wn = wid & 1;
    const int m0 = (tile / ntn) * 128;
    const int n0 = (tile % ntn) * 128;

    const int a_r = t >> 3;
    const int a_c4 = t & 7;
    const int b_col = t & 127;
    const int b_kq0 = t >> 7;

    f32x4 acc[4][4];
#pragma unroll
    for (int i = 0; i < 4; ++i)
#pragma unroll
        for (int j = 0; j < 4; ++j) acc[i][j] = (f32x4)(0.f);

    for (int k0 = 0; k0 < K_DIM; k0 += 32) {
        __syncthreads();
#pragma unroll
        for (int p = 0; p < 4; ++p) {
            const int row = a_r + p * 32;
            const int grow = min(m0 + row, M - 1);
            const float4 v = *(const float4*)(A + (size_t)grow * K_DIM + k0 + a_c4 * 4);
            unsigned short h0 = bf16_hi(v.x), h1 = bf16_hi(v.y),
                           h2 = bf16_hi(v.z), h3 = bf16_hi(v.w);
            unsigned short l0 = bf16_hi(v.x - bf16_back(h0)),
                           l1 = bf16_hi(v.y - bf16_back(h1)),
                           l2 = bf16_hi(v.z - bf16_back(h2)),
                           l3 = bf16_hi(v.w - bf16_back(h3));
            *(ushort4*)&As_hi[row][a_c4 * 4] = make_ushort4(h0, h1, h2, h3);
            *(ushort4*)&As_lo[row][a_c4 * 4] = make_ushort4(l0, l1, l2, l3);
        }
#pragma unroll
        for (int p = 0; p < 4; ++p) {
            const int kq = b_kq0 + p * 2;
            float v0 = B[(size_t)(k0 + kq * 4 + 0) * NCOLS + n0 + b_col];
            float v1 = B[(size_t)(k0 + kq * 4 + 1) * NCOLS + n0 + b_col];
            float v2 = B[(size_t)(k0 + kq * 4 + 2) * NCOLS + n0 + b_col];
            float v3 = B[(size_t)(k0 + kq * 4 + 3) * NCOLS + n0 + b_col];
            unsigned short h0 = bf16_hi(v0), h1 = bf16_hi(v1),
                           h2 = bf16_hi(v2), h3 = bf16_hi(v3);
            unsigned short l0 = bf16_hi(v0 - bf16_back(h0)),
                           l1 = bf16_hi(v1 - bf16_back(h1)),
                           l2 = bf16_hi(v2 - bf16_back(h2)),
                           l3 = bf16_hi(v3 - bf16_back(h3));
            *(ushort4*)&Bs_hi[b_col][kq * 4] = make_ushort4(h0, h1, h2, h3);
            *(ushort4*)&Bs_lo[b_col][kq * 4] = make_ushort4(l0, l1, l2, l3);
        }
        __syncthreads();

        const int fr = lane & 15;
        const int fk = (lane >> 4) * 8;
        short8 a_hi[4], a_lo[4], b_hi[4], b_lo[4];
#pragma unroll
        for (int fm = 0; fm < 4; ++fm) {
            const int r = wm * 64 + fm * 16 + fr;
            a_hi[fm] = *(const short8*)&As_hi[r][fk];
            a_lo[fm] = *(const short8*)&As_lo[r][fk];
        }
#pragma unroll
        for (int fn = 0; fn < 4; ++fn) {
            const int c = wn * 64 + fn * 16 + fr;
            b_hi[fn] = *(const short8*)&Bs_hi[c][fk];
            b_lo[fn] = *(const short8*)&Bs_lo[c][fk];
        }
#pragma unroll
        for (int fm = 0; fm < 4; ++fm)
#pragma unroll
            for (int fn = 0; fn < 4; ++fn) {
                acc[fm][fn] = __builtin_amdgcn_mfma_f32_16x16x32_bf16(
                    a_hi[fm], b_hi[fn], acc[fm][fn], 0, 0, 0);
                acc[fm][fn] = __builtin_amdgcn_mfma_f32_16x16x32_bf16(
                    a_hi[fm], b_lo[fn], acc[fm][fn], 0, 0, 0);
                acc[fm][fn] = __builtin_amdgcn_mfma_f32_16x16x32_bf16(
                    a_lo[fm], b_hi[fn], acc[fm][fn], 0, 0, 0);
            }
    }

    const int c_col = n0 + wn * 64 + (lane & 15);
    const int r_base = m0 + wm * 64 + (lane >> 4) * 4;
#pragma unroll
    for (int fm = 0; fm < 4; ++fm)
#pragma unroll
        for (int fn = 0; fn < 4; ++fn)
#pragma unroll
            for (int r = 0; r < 4; ++r) {
                const int row = r_base + fm * 16 + r;
                if (row < M)
                    C[(size_t)row * NCOLS + c_col + fn * 16] = bf16_hi(acc[fm][fn][r]);
            }
}

template <int F, bool RELU>
__global__ __launch_bounds__(256) void aggregate_kernel(
    const unsigned short* __restrict__ xw, const int* __restrict__ row_ptr,
    const int* __restrict__ col, const float* __restrict__ wnorm,
    const float* __restrict__ dis, const float* __restrict__ bias,
    float* __restrict__ out, int N) {
    constexpr int VEC = F / 64;
    const int wid = threadIdx.x >> 6;
    const int lane = threadIdx.x & 63;
    const int n = blockIdx.x * 4 + wid;
    if (n >= N) return;

    const float dn = dis[n];
    float acc[VEC];
    {
        const float w = dn * dn;
        const unsigned short* xn = xw + (size_t)n * F + lane * VEC;
        if (VEC == 4) {
            const ushort4 u = *(const ushort4*)xn;
            acc[0] = bf2f(u.x) * w;
            acc[1] = bf2f(u.y) * w;
            acc[2] = bf2f(u.z) * w;
            acc[3] = bf2f(u.w) * w;
        } else {
            const ushort2 u = *(const ushort2*)xn;
            acc[0] = bf2f(u.x) * w;
            acc[1] = bf2f(u.y) * w;
        }
    }

    const int e0 = row_ptr[n];
    const int e1 = row_ptr[n + 1];
    int e = e0;
    for (; e + 2 <= e1; e += 2) {
        const int s0 = col[e];
        const int s1 = col[e + 1];
        const float w0 = wnorm[e];
        const float w1 = wnorm[e + 1];
        const unsigned short* x0 = xw + (size_t)s0 * F + lane * VEC;
        const unsigned short* x1 = xw + (size_t)s1 * F + lane * VEC;
        if (VEC == 4) {
            const ushort4 u0 = *(const ushort4*)x0;
            const ushort4 u1 = *(const ushort4*)x1;
            acc[0] += bf2f(u0.x) * w0 + bf2f(u1.x) * w1;
            acc[1] += bf2f(u0.y) * w0 + bf2f(u1.y) * w1;
            acc[2] += bf2f(u0.z) * w0 + bf2f(u1.z) * w1;
            acc[3] += bf2f(u0.w) * w0 + bf2f(u1.w) * w1;
        } else {
            const ushort2 u0 = *(const ushort2*)x0;
            const ushort2 u1 = *(const ushort2*)x1;
            acc[0] += bf2f(u0.x) * w0 + bf2f(u1.x) * w1;
            acc[1] += bf2f(u0.y) * w0 + bf2f(u1.y) * w1;
        }
    }
    if (e < e1) {
        const int s0 = col[e];
        const float w0 = wnorm[e];
        const unsigned short* x0 = xw + (size_t)s0 * F + lane * VEC;
        if (VEC == 4) {
            const ushort4 u0 = *(const ushort4*)x0;
            acc[0] += bf2f(u0.x) * w0;
            acc[1] += bf2f(u0.y) * w0;
            acc[2] += bf2f(u0.z) * w0;
            acc[3] += bf2f(u0.w) * w0;
        } else {
            const ushort2 u0 = *(const ushort2*)x0;
            acc[0] += bf2f(u0.x) * w0;
            acc[1] += bf2f(u0.y) * w0;
        }
    }

    float* o = out + (size_t)n * F + lane * VEC;
#pragma unroll
    for (int v = 0; v < VEC; ++v) {
        float r = acc[v] + bias[lane * VEC + v];
        if (RELU) r = fmaxf(r, 0.f);
        o[v] = r;
    }
}

// ---------------------------------------------------------------------------
// Launch
// ---------------------------------------------------------------------------

extern "C" void kernel_launch(void* const* d_in, const int* in_sizes, int n_in,
                              void* d_out, int out_size, void* d_ws, size_t ws_size,
                              hipStream_t stream) {
    const float* x = (const float*)d_in[0];
    const int* edge = (const int*)d_in[1];
    const float* W1 = (const float*)d_in[2];
    const float* b1 = (const float*)d_in[3];
    const float* W2 = (const float*)d_in[4];
    const float* b2 = (const float*)d_in[5];

    const int N = in_sizes[0] / 256;   // 50000
    const int E = in_sizes[1] / 2;     // 800000
    const int* src = edge;
    const int* dst = edge + E;

    char* w = (char*)d_ws;
    auto carve = [&](size_t bytes) {
        char* p = w;
        w += (bytes + 255) & ~(size_t)255;
        return p;
    };
    const int nscan = (N + SCAN_C - 1) / SCAN_C;   // 98
    int* cnt = (int*)carve((size_t)N * 4);
    int* row_ptr = (int*)carve((size_t)(N + 1) * 4);
    int* fill = (int*)carve((size_t)N * 4);
    int* col = (int*)carve((size_t)E * 4);
    float* wnorm = (float*)carve((size_t)E * 4);
    float* dis = (float*)carve((size_t)N * 4);
    int* bsum = (int*)carve((size_t)nscan * 4);
    unsigned short* xw1 = (unsigned short*)carve((size_t)N * 256 * 2);  // bf16
    float* h = (float*)carve((size_t)N * 256 * 4);                      // fp32
    unsigned short* xw2 = xw1;  // alias: xw1 dead after aggregate1

    float* out = (float*)d_out;

    Params p;
    p.x = x; p.src = src; p.dst = dst;
    p.W1 = W1; p.b1 = b1; p.W2 = W2; p.b2 = b2;
    p.N = N; p.E = E; p.nscan = nscan;
    p.cnt = cnt; p.row_ptr = row_ptr; p.fill = fill; p.col = col; p.bsum = bsum;
    p.wnorm = wnorm; p.dis = dis; p.h = h;
    p.xw1 = xw1; p.xw2 = xw2; p.out = out;

    void* args[] = {(void*)&p};
    hipError_t err = hipLaunchCooperativeKernel((const void*)fused_kernel,
                                                dim3(GRIDN), dim3(BLK), args, 0, stream);
    if (err == hipSuccess) return;

    // ---- fallback: proven round-8 multi-kernel path ----
    hipMemsetAsync(cnt, 0, (size_t)N * 4, stream);
    const int eblocks = (E + 255) / 256;
    degree_hist_kernel<<<eblocks, 256, 0, stream>>>(dst, E, cnt);
    scan_phase1<<<nscan, 256, 0, stream>>>(cnt, bsum, N);
    scan_phase2<<<1, 256, 0, stream>>>(bsum, nscan, row_ptr, N);
    scan_phase3<<<nscan, 256, 0, stream>>>(cnt, bsum, row_ptr, fill, dis, N);
    build_csr_kernel<<<eblocks, 256, 0, stream>>>(src, dst, E, fill, col, dis, wnorm);
    {
        dim3 grid(2 * ((N + 127) / 128));
        gemm_mfma_kernel<256><<<grid, 256, 0, stream>>>(x, W1, xw1, N);
    }
    aggregate_kernel<256, true><<<(N + 3) / 4, 256, 0, stream>>>(
        xw1, row_ptr, col, wnorm, dis, b1, h, N);
    {
        dim3 grid((N + 127) / 128);
        gemm_mfma_kernel<128><<<grid, 256, 0, stream>>>(h, W2, xw2, N);
    }
    aggregate_kernel<128, false><<<(N + 3) / 4, 256, 0, stream>>>(
        xw2, row_ptr, col, wnorm, dis, b2, out, N);
}

// Round 12
// 885.301 us; speedup vs baseline: 1.3654x; 1.3654x over previous
//
#include <hip/hip_runtime.h>
#include <hip/hip_bf16.h>
#include <hip/hip_cooperative_groups.h>

namespace cg = cooperative_groups;

#define K_DIM 256
constexpr int BLK = 256;
constexpr int SCAN_C = 512;     // cnt elements per scan block (2 per thread)
constexpr int CSR_GRID = 1024;  // 4 blocks/CU, forced by __launch_bounds__(256,4)

typedef __attribute__((ext_vector_type(8))) short short8;
typedef __attribute__((ext_vector_type(4))) float f32x4;

// ---------------------------------------------------------------------------
// bf16 helpers
// ---------------------------------------------------------------------------

__device__ __forceinline__ unsigned short bf16_hi(float v) {
    __hip_bfloat16 h = __float2bfloat16(v);
    return *(unsigned short*)&h;
}
__device__ __forceinline__ float bf16_back(unsigned short u) {
    __hip_bfloat16 h = *(__hip_bfloat16*)&u;
    return __bfloat162float(h);
}
__device__ __forceinline__ float bf2f(unsigned short u) {
    unsigned int b = ((unsigned int)u) << 16;
    float f;
    __builtin_memcpy(&f, &b, 4);
    return f;
}

// ---------------------------------------------------------------------------
// Cooperative CSR-build kernel: memset + histogram + 3-phase scan + scatter.
// All phases are low-VGPR (<=~32) so __launch_bounds__(256,4) costs nothing;
// 1024 blocks co-resident on 256 CUs -> grid.sync safe. Replaces 6 separate
// launches (5 gaps removed). GEMM/agg stay standalone at their own optimal
// register/occupancy points (round-11 lesson: one bound can't serve both).
// ---------------------------------------------------------------------------

struct CsrParams {
    const int* src;
    const int* dst;
    int N, E, nscan;
    int* cnt;
    int* row_ptr;
    int* fill;
    int* col;
    int* bsum;
    float* wnorm;
    float* dis;
};

__global__ void __launch_bounds__(256, 4) csr_fused_kernel(CsrParams p) {
    __shared__ int sh[256];
    cg::grid_group grid = cg::this_grid();
    const int t = threadIdx.x;
    const int bid = blockIdx.x;
    const int gtid = bid * BLK + t;
    const int gsize = CSR_GRID * BLK;

    // P0: zero cnt
    for (int i = gtid; i < p.N; i += gsize) p.cnt[i] = 0;
    grid.sync();

    // P1: degree histogram of dst
    for (int e = gtid; e < p.E; e += gsize) atomicAdd(&p.cnt[p.dst[e]], 1);
    grid.sync();

    // P2: per-block partial sums of cnt
    if (bid < p.nscan) {
        const int i0 = bid * SCAN_C + 2 * t;
        int s = 0;
        if (i0 < p.N) s += p.cnt[i0];
        if (i0 + 1 < p.N) s += p.cnt[i0 + 1];
        sh[t] = s;
        __syncthreads();
        for (int off = 128; off > 0; off >>= 1) {
            if (t < off) sh[t] += sh[t + off];
            __syncthreads();
        }
        if (t == 0) p.bsum[bid] = sh[0];
    }
    grid.sync();

    // P3: block 0 scans the block sums (nscan <= 256)
    if (bid == 0) {
        int v = (t < p.nscan) ? p.bsum[t] : 0;
        sh[t] = v;
        __syncthreads();
        for (int off = 1; off < 256; off <<= 1) {
            int u = (t >= off) ? sh[t - off] : 0;
            __syncthreads();
            sh[t] += u;
            __syncthreads();
        }
        if (t < p.nscan) p.bsum[t] = (t == 0) ? 0 : sh[t - 1];
        if (t == 255) p.row_ptr[p.N] = sh[255];
    }
    grid.sync();

    // P4: local scan + block offset -> row_ptr, fill, dis
    if (bid < p.nscan) {
        const int i0 = bid * SCAN_C + 2 * t;
        const int c0 = (i0 < p.N) ? p.cnt[i0] : 0;
        const int c1 = (i0 + 1 < p.N) ? p.cnt[i0 + 1] : 0;
        sh[t] = c0 + c1;
        __syncthreads();
        for (int off = 1; off < 256; off <<= 1) {
            int u = (t >= off) ? sh[t - off] : 0;
            __syncthreads();
            sh[t] += u;
            __syncthreads();
        }
        const int excl = ((t == 0) ? 0 : sh[t - 1]) + p.bsum[bid];
        if (i0 < p.N) {
            p.row_ptr[i0] = excl;
            p.fill[i0] = excl;
            p.dis[i0] = rsqrtf((float)(c0 + 1));
        }
        if (i0 + 1 < p.N) {
            p.row_ptr[i0 + 1] = excl + c0;
            p.fill[i0 + 1] = excl + c0;
            p.dis[i0 + 1] = rsqrtf((float)(c1 + 1));
        }
    }
    grid.sync();

    // P5: CSR scatter + per-edge weights
    for (int e = gtid; e < p.E; e += gsize) {
        const int s = p.src[e];
        const int d = p.dst[e];
        const int pos = atomicAdd(&p.fill[d], 1);
        p.col[pos] = s;
        p.wnorm[pos] = p.dis[s] * p.dis[d];
    }
}

// ---------------------------------------------------------------------------
// Fallback CSR kernels (used only if cooperative launch is rejected).
// ---------------------------------------------------------------------------

__global__ void degree_hist_kernel(const int* __restrict__ dst, int E,
                                   int* __restrict__ cnt) {
    int e = blockIdx.x * blockDim.x + threadIdx.x;
    if (e < E) atomicAdd(&cnt[dst[e]], 1);
}

__global__ __launch_bounds__(256) void scan_phase1(const int* __restrict__ cnt,
                                                   int* __restrict__ bsum, int N) {
    const int t = threadIdx.x;
    const int i0 = blockIdx.x * SCAN_C + 2 * t;
    int s = 0;
    if (i0 < N) s += cnt[i0];
    if (i0 + 1 < N) s += cnt[i0 + 1];
    __shared__ int sh[256];
    sh[t] = s;
    __syncthreads();
    for (int off = 128; off > 0; off >>= 1) {
        if (t < off) sh[t] += sh[t + off];
        __syncthreads();
    }
    if (t == 0) bsum[blockIdx.x] = sh[0];
}

__global__ __launch_bounds__(256) void scan_phase2(int* __restrict__ bsum, int nb,
                                                   int* __restrict__ row_ptr, int N) {
    const int t = threadIdx.x;
    int v = (t < nb) ? bsum[t] : 0;
    __shared__ int sh[256];
    sh[t] = v;
    __syncthreads();
    for (int off = 1; off < 256; off <<= 1) {
        int u = (t >= off) ? sh[t - off] : 0;
        __syncthreads();
        sh[t] += u;
        __syncthreads();
    }
    if (t < nb) bsum[t] = (t == 0) ? 0 : sh[t - 1];
    if (t == 255) row_ptr[N] = sh[255];
}

__global__ __launch_bounds__(256) void scan_phase3(const int* __restrict__ cnt,
                                                   const int* __restrict__ bsum,
                                                   int* __restrict__ row_ptr,
                                                   int* __restrict__ fill,
                                                   float* __restrict__ dis, int N) {
    const int t = threadIdx.x;
    const int i0 = blockIdx.x * SCAN_C + 2 * t;
    const int c0 = (i0 < N) ? cnt[i0] : 0;
    const int c1 = (i0 + 1 < N) ? cnt[i0 + 1] : 0;
    __shared__ int sh[256];
    sh[t] = c0 + c1;
    __syncthreads();
    for (int off = 1; off < 256; off <<= 1) {
        int u = (t >= off) ? sh[t - off] : 0;
        __syncthreads();
        sh[t] += u;
        __syncthreads();
    }
    const int excl = ((t == 0) ? 0 : sh[t - 1]) + bsum[blockIdx.x];
    if (i0 < N) {
        row_ptr[i0] = excl;
        fill[i0] = excl;
        dis[i0] = rsqrtf((float)(c0 + 1));
    }
    if (i0 + 1 < N) {
        row_ptr[i0 + 1] = excl + c0;
        fill[i0 + 1] = excl + c0;
        dis[i0 + 1] = rsqrtf((float)(c1 + 1));
    }
}

__global__ void build_csr_kernel(const int* __restrict__ src,
                                 const int* __restrict__ dst, int E,
                                 int* __restrict__ fill, int* __restrict__ col,
                                 const float* __restrict__ dis,
                                 float* __restrict__ wnorm) {
    int e = blockIdx.x * blockDim.x + threadIdx.x;
    if (e < E) {
        int s = src[e];
        int d = dst[e];
        int pos = atomicAdd(&fill[d], 1);
        col[pos] = s;
        wnorm[pos] = dis[s] * dis[d];
    }
}

// ---------------------------------------------------------------------------
// MFMA bf16x3 (split-fp32) GEMM (round-8 proven): C = bf16(A[M,256] @ B[256,N]).
// No min-waves bound: the GEMM wants its natural ~100 VGPR (round-11 lesson:
// forcing 3 blocks/CU spilled the accumulators to scratch, 3x regression).
// ---------------------------------------------------------------------------

template <int NCOLS>
__global__ __launch_bounds__(256) void gemm_mfma_kernel(const float* __restrict__ A,
                                                        const float* __restrict__ B,
                                                        unsigned short* __restrict__ C,
                                                        int M) {
    __shared__ unsigned short lds[4 * 128 * 40];
    const int t = threadIdx.x;
    const int ntn = NCOLS / 128;
    const int tile = blockIdx.x;
    unsigned short(*As_hi)[40] = (unsigned short(*)[40])(lds);
    unsigned short(*As_lo)[40] = (unsigned short(*)[40])(lds + 128 * 40);
    unsigned short(*Bs_hi)[40] = (unsigned short(*)[40])(lds + 2 * 128 * 40);
    unsigned short(*Bs_lo)[40] = (unsigned short(*)[40])(lds + 3 * 128 * 40);

    const int lane = t & 63;
    const int wid = t >> 6;
    const int wm = wid >> 1;
    const int wn = wid & 1;
    const int m0 = (tile / ntn) * 128;
    const int n0 = (tile % ntn) * 128;

    const int a_r = t >> 3;
    const int a_c4 = t & 7;
    const int b_col = t & 127;
    const int b_kq0 = t >> 7;

    f32x4 acc[4][4];
#pragma unroll
    for (int i = 0; i < 4; ++i)
#pragma unroll
        for (int j = 0; j < 4; ++j) acc[i][j] = (f32x4)(0.f);

    for (int k0 = 0; k0 < K_DIM; k0 += 32) {
        __syncthreads();
#pragma unroll
        for (int p = 0; p < 4; ++p) {
            const int row = a_r + p * 32;
            const int grow = min(m0 + row, M - 1);
            const float4 v = *(const float4*)(A + (size_t)grow * K_DIM + k0 + a_c4 * 4);
            unsigned short h0 = bf16_hi(v.x), h1 = bf16_hi(v.y),
                           h2 = bf16_hi(v.z), h3 = bf16_hi(v.w);
            unsigned short l0 = bf16_hi(v.x - bf16_back(h0)),
                           l1 = bf16_hi(v.y - bf16_back(h1)),
                           l2 = bf16_hi(v.z - bf16_back(h2)),
                           l3 = bf16_hi(v.w - bf16_back(h3));
            *(ushort4*)&As_hi[row][a_c4 * 4] = make_ushort4(h0, h1, h2, h3);
            *(ushort4*)&As_lo[row][a_c4 * 4] = make_ushort4(l0, l1, l2, l3);
        }
#pragma unroll
        for (int p = 0; p < 4; ++p) {
            const int kq = b_kq0 + p * 2;
            float v0 = B[(size_t)(k0 + kq * 4 + 0) * NCOLS + n0 + b_col];
            float v1 = B[(size_t)(k0 + kq * 4 + 1) * NCOLS + n0 + b_col];
            float v2 = B[(size_t)(k0 + kq * 4 + 2) * NCOLS + n0 + b_col];
            float v3 = B[(size_t)(k0 + kq * 4 + 3) * NCOLS + n0 + b_col];
            unsigned short h0 = bf16_hi(v0), h1 = bf16_hi(v1),
                           h2 = bf16_hi(v2), h3 = bf16_hi(v3);
            unsigned short l0 = bf16_hi(v0 - bf16_back(h0)),
                           l1 = bf16_hi(v1 - bf16_back(h1)),
                           l2 = bf16_hi(v2 - bf16_back(h2)),
                           l3 = bf16_hi(v3 - bf16_back(h3));
            *(ushort4*)&Bs_hi[b_col][kq * 4] = make_ushort4(h0, h1, h2, h3);
            *(ushort4*)&Bs_lo[b_col][kq * 4] = make_ushort4(l0, l1, l2, l3);
        }
        __syncthreads();

        const int fr = lane & 15;
        const int fk = (lane >> 4) * 8;
        short8 a_hi[4], a_lo[4], b_hi[4], b_lo[4];
#pragma unroll
        for (int fm = 0; fm < 4; ++fm) {
            const int r = wm * 64 + fm * 16 + fr;
            a_hi[fm] = *(const short8*)&As_hi[r][fk];
            a_lo[fm] = *(const short8*)&As_lo[r][fk];
        }
#pragma unroll
        for (int fn = 0; fn < 4; ++fn) {
            const int c = wn * 64 + fn * 16 + fr;
            b_hi[fn] = *(const short8*)&Bs_hi[c][fk];
            b_lo[fn] = *(const short8*)&Bs_lo[c][fk];
        }
#pragma unroll
        for (int fm = 0; fm < 4; ++fm)
#pragma unroll
            for (int fn = 0; fn < 4; ++fn) {
                acc[fm][fn] = __builtin_amdgcn_mfma_f32_16x16x32_bf16(
                    a_hi[fm], b_hi[fn], acc[fm][fn], 0, 0, 0);
                acc[fm][fn] = __builtin_amdgcn_mfma_f32_16x16x32_bf16(
                    a_hi[fm], b_lo[fn], acc[fm][fn], 0, 0, 0);
                acc[fm][fn] = __builtin_amdgcn_mfma_f32_16x16x32_bf16(
                    a_lo[fm], b_hi[fn], acc[fm][fn], 0, 0, 0);
            }
    }

    const int c_col = n0 + wn * 64 + (lane & 15);
    const int r_base = m0 + wm * 64 + (lane >> 4) * 4;
#pragma unroll
    for (int fm = 0; fm < 4; ++fm)
#pragma unroll
        for (int fn = 0; fn < 4; ++fn)
#pragma unroll
            for (int r = 0; r < 4; ++r) {
                const int row = r_base + fm * 16 + r;
                if (row < M)
                    C[(size_t)row * NCOLS + c_col + fn * 16] = bf16_hi(acc[fm][fn][r]);
            }
}

// ---------------------------------------------------------------------------
// CSR aggregation over bf16 features; edge loop unrolled x4 (latency-bound
// gather: more outstanding requests per wave; VALUBusy was 29%).
// ---------------------------------------------------------------------------

template <int F, bool RELU>
__global__ __launch_bounds__(256) void aggregate_kernel(
    const unsigned short* __restrict__ xw, const int* __restrict__ row_ptr,
    const int* __restrict__ col, const float* __restrict__ wnorm,
    const float* __restrict__ dis, const float* __restrict__ bias,
    float* __restrict__ out, int N) {
    constexpr int VEC = F / 64;
    const int wid = threadIdx.x >> 6;
    const int lane = threadIdx.x & 63;
    const int n = blockIdx.x * 4 + wid;
    if (n >= N) return;

    const float dn = dis[n];
    float acc[VEC];
    {
        const float w = dn * dn;
        const unsigned short* xn = xw + (size_t)n * F + lane * VEC;
        if (VEC == 4) {
            const ushort4 u = *(const ushort4*)xn;
            acc[0] = bf2f(u.x) * w;
            acc[1] = bf2f(u.y) * w;
            acc[2] = bf2f(u.z) * w;
            acc[3] = bf2f(u.w) * w;
        } else {
            const ushort2 u = *(const ushort2*)xn;
            acc[0] = bf2f(u.x) * w;
            acc[1] = bf2f(u.y) * w;
        }
    }

    const int e0 = row_ptr[n];
    const int e1 = row_ptr[n + 1];
    int e = e0;
    for (; e + 4 <= e1; e += 4) {
        const int s0 = col[e], s1 = col[e + 1], s2 = col[e + 2], s3 = col[e + 3];
        const float w0 = wnorm[e], w1 = wnorm[e + 1], w2 = wnorm[e + 2], w3 = wnorm[e + 3];
        const unsigned short* x0 = xw + (size_t)s0 * F + lane * VEC;
        const unsigned short* x1 = xw + (size_t)s1 * F + lane * VEC;
        const unsigned short* x2 = xw + (size_t)s2 * F + lane * VEC;
        const unsigned short* x3 = xw + (size_t)s3 * F + lane * VEC;
        if (VEC == 4) {
            const ushort4 u0 = *(const ushort4*)x0;
            const ushort4 u1 = *(const ushort4*)x1;
            const ushort4 u2 = *(const ushort4*)x2;
            const ushort4 u3 = *(const ushort4*)x3;
            acc[0] += bf2f(u0.x) * w0 + bf2f(u1.x) * w1 + bf2f(u2.x) * w2 + bf2f(u3.x) * w3;
            acc[1] += bf2f(u0.y) * w0 + bf2f(u1.y) * w1 + bf2f(u2.y) * w2 + bf2f(u3.y) * w3;
            acc[2] += bf2f(u0.z) * w0 + bf2f(u1.z) * w1 + bf2f(u2.z) * w2 + bf2f(u3.z) * w3;
            acc[3] += bf2f(u0.w) * w0 + bf2f(u1.w) * w1 + bf2f(u2.w) * w2 + bf2f(u3.w) * w3;
        } else {
            const ushort2 u0 = *(const ushort2*)x0;
            const ushort2 u1 = *(const ushort2*)x1;
            const ushort2 u2 = *(const ushort2*)x2;
            const ushort2 u3 = *(const ushort2*)x3;
            acc[0] += bf2f(u0.x) * w0 + bf2f(u1.x) * w1 + bf2f(u2.x) * w2 + bf2f(u3.x) * w3;
            acc[1] += bf2f(u0.y) * w0 + bf2f(u1.y) * w1 + bf2f(u2.y) * w2 + bf2f(u3.y) * w3;
        }
    }
    for (; e < e1; ++e) {
        const int s0 = col[e];
        const float w0 = wnorm[e];
        const unsigned short* x0 = xw + (size_t)s0 * F + lane * VEC;
        if (VEC == 4) {
            const ushort4 u0 = *(const ushort4*)x0;
            acc[0] += bf2f(u0.x) * w0;
            acc[1] += bf2f(u0.y) * w0;
            acc[2] += bf2f(u0.z) * w0;
            acc[3] += bf2f(u0.w) * w0;
        } else {
            const ushort2 u0 = *(const ushort2*)x0;
            acc[0] += bf2f(u0.x) * w0;
            acc[1] += bf2f(u0.y) * w0;
        }
    }

    float* o = out + (size_t)n * F + lane * VEC;
#pragma unroll
    for (int v = 0; v < VEC; ++v) {
        float r = acc[v] + bias[lane * VEC + v];
        if (RELU) r = fmaxf(r, 0.f);
        o[v] = r;
    }
}

// ---------------------------------------------------------------------------
// Launch
// ---------------------------------------------------------------------------

extern "C" void kernel_launch(void* const* d_in, const int* in_sizes, int n_in,
                              void* d_out, int out_size, void* d_ws, size_t ws_size,
                              hipStream_t stream) {
    const float* x = (const float*)d_in[0];
    const int* edge = (const int*)d_in[1];
    const float* W1 = (const float*)d_in[2];
    const float* b1 = (const float*)d_in[3];
    const float* W2 = (const float*)d_in[4];
    const float* b2 = (const float*)d_in[5];

    const int N = in_sizes[0] / 256;   // 50000
    const int E = in_sizes[1] / 2;     // 800000
    const int* src = edge;
    const int* dst = edge + E;

    char* w = (char*)d_ws;
    auto carve = [&](size_t bytes) {
        char* p = w;
        w += (bytes + 255) & ~(size_t)255;
        return p;
    };
    const int nscan = (N + SCAN_C - 1) / SCAN_C;   // 98
    int* cnt = (int*)carve((size_t)N * 4);
    int* row_ptr = (int*)carve((size_t)(N + 1) * 4);
    int* fill = (int*)carve((size_t)N * 4);
    int* col = (int*)carve((size_t)E * 4);
    float* wnorm = (float*)carve((size_t)E * 4);
    float* dis = (float*)carve((size_t)N * 4);
    int* bsum = (int*)carve((size_t)nscan * 4);
    unsigned short* xw1 = (unsigned short*)carve((size_t)N * 256 * 2);  // bf16
    float* h = (float*)carve((size_t)N * 256 * 4);                      // fp32
    unsigned short* xw2 = xw1;  // alias: xw1 dead after aggregate1

    float* out = (float*)d_out;

    // ---- CSR build: one cooperative launch (replaces 6 small launches) ----
    CsrParams cp;
    cp.src = src; cp.dst = dst;
    cp.N = N; cp.E = E; cp.nscan = nscan;
    cp.cnt = cnt; cp.row_ptr = row_ptr; cp.fill = fill; cp.col = col;
    cp.bsum = bsum; cp.wnorm = wnorm; cp.dis = dis;

    void* args[] = {(void*)&cp};
    hipError_t err = hipLaunchCooperativeKernel((const void*)csr_fused_kernel,
                                                dim3(CSR_GRID), dim3(BLK), args, 0, stream);
    if (err != hipSuccess) {
        // fallback: separate proven kernels
        hipMemsetAsync(cnt, 0, (size_t)N * 4, stream);
        const int eblocks = (E + 255) / 256;
        degree_hist_kernel<<<eblocks, 256, 0, stream>>>(dst, E, cnt);
        scan_phase1<<<nscan, 256, 0, stream>>>(cnt, bsum, N);
        scan_phase2<<<1, 256, 0, stream>>>(bsum, nscan, row_ptr, N);
        scan_phase3<<<nscan, 256, 0, stream>>>(cnt, bsum, row_ptr, fill, dis, N);
        build_csr_kernel<<<eblocks, 256, 0, stream>>>(src, dst, E, fill, col, dis, wnorm);
    }

    // ---- layer 1: xw1 = bf16(x @ W1) ; h = agg(xw1)+b1, ReLU ----
    {
        dim3 grid(2 * ((N + 127) / 128));
        gemm_mfma_kernel<256><<<grid, 256, 0, stream>>>(x, W1, xw1, N);
    }
    aggregate_kernel<256, true><<<(N + 3) / 4, 256, 0, stream>>>(
        xw1, row_ptr, col, wnorm, dis, b1, h, N);

    // ---- layer 2: xw2 = bf16(h @ W2) ; out = agg(xw2)+b2 ----
    {
        dim3 grid((N + 127) / 128);
        gemm_mfma_kernel<128><<<grid, 256, 0, stream>>>(h, W2, xw2, N);
    }
    aggregate_kernel<128, false><<<(N + 3) / 4, 256, 0, stream>>>(
        xw2, row_ptr, col, wnorm, dis, b2, out, N);
}

// Round 13
// 337.331 us; speedup vs baseline: 3.5834x; 2.6244x over previous
//
#include <hip/hip_runtime.h>
#include <hip/hip_bf16.h>

#define K_DIM 256
constexpr int SCAN_C = 512;  // cnt elements per scan block (2 per thread)

typedef __attribute__((ext_vector_type(8))) short short8;
typedef __attribute__((ext_vector_type(4))) float f32x4;

// NOTE (measured, round 11/12): cg::grid_group::sync() costs ~100us on MI355X
// (8-XCD device-scope barrier spin; 109MB of atomic spin traffic per launch).
// Launch gaps are ~15-18us. Multi-kernel beats cooperative fusion here.

// ---------------------------------------------------------------------------
// bf16 helpers
// ---------------------------------------------------------------------------

__device__ __forceinline__ unsigned short bf16_hi(float v) {
    __hip_bfloat16 h = __float2bfloat16(v);
    return *(unsigned short*)&h;
}
__device__ __forceinline__ float bf16_back(unsigned short u) {
    __hip_bfloat16 h = *(__hip_bfloat16*)&u;
    return __bfloat162float(h);
}
__device__ __forceinline__ float bf2f(unsigned short u) {
    unsigned int b = ((unsigned int)u) << 16;
    float f;
    __builtin_memcpy(&f, &b, 4);
    return f;
}

// ---------------------------------------------------------------------------
// CSR build: histogram, scan1 (block sums), scan23 (merged: every block
// redundantly scans the <=256 block sums in LDS -> one fewer launch), scatter.
// ---------------------------------------------------------------------------

__global__ void degree_hist_kernel(const int* __restrict__ dst, int E,
                                   int* __restrict__ cnt) {
    int e = blockIdx.x * blockDim.x + threadIdx.x;
    if (e < E) atomicAdd(&cnt[dst[e]], 1);
}

__global__ __launch_bounds__(256) void scan_phase1(const int* __restrict__ cnt,
                                                   int* __restrict__ bsum, int N) {
    const int t = threadIdx.x;
    const int i0 = blockIdx.x * SCAN_C + 2 * t;
    int s = 0;
    if (i0 < N) s += cnt[i0];
    if (i0 + 1 < N) s += cnt[i0 + 1];
    __shared__ int sh[256];
    sh[t] = s;
    __syncthreads();
    for (int off = 128; off > 0; off >>= 1) {
        if (t < off) sh[t] += sh[t + off];
        __syncthreads();
    }
    if (t == 0) bsum[blockIdx.x] = sh[0];
}

// Merged scan phases 2+3: redundant in-block scan of bsum (nscan <= 256),
// then local scan + offset -> row_ptr, fill, dis.
__global__ __launch_bounds__(256) void scan_phase23(const int* __restrict__ cnt,
                                                    const int* __restrict__ bsum,
                                                    int nscan,
                                                    int* __restrict__ row_ptr,
                                                    int* __restrict__ fill,
                                                    float* __restrict__ dis, int N) {
    __shared__ int sb[256];
    __shared__ int sh[256];
    const int t = threadIdx.x;
    const int bid = blockIdx.x;

    // scan block sums (inclusive) in every block
    sb[t] = (t < nscan) ? bsum[t] : 0;
    __syncthreads();
    for (int off = 1; off < 256; off <<= 1) {
        int u = (t >= off) ? sb[t - off] : 0;
        __syncthreads();
        sb[t] += u;
        __syncthreads();
    }
    const int block_off = (bid == 0) ? 0 : sb[bid - 1];
    if (bid == 0 && t == 0) row_ptr[N] = sb[nscan - 1];

    // local scan of this block's 512 cnt values
    const int i0 = bid * SCAN_C + 2 * t;
    const int c0 = (i0 < N) ? cnt[i0] : 0;
    const int c1 = (i0 + 1 < N) ? cnt[i0 + 1] : 0;
    sh[t] = c0 + c1;
    __syncthreads();
    for (int off = 1; off < 256; off <<= 1) {
        int u = (t >= off) ? sh[t - off] : 0;
        __syncthreads();
        sh[t] += u;
        __syncthreads();
    }
    const int excl = ((t == 0) ? 0 : sh[t - 1]) + block_off;
    if (i0 < N) {
        row_ptr[i0] = excl;
        fill[i0] = excl;
        dis[i0] = rsqrtf((float)(c0 + 1));
    }
    if (i0 + 1 < N) {
        row_ptr[i0 + 1] = excl + c0;
        fill[i0 + 1] = excl + c0;
        dis[i0 + 1] = rsqrtf((float)(c1 + 1));
    }
}

__global__ void build_csr_kernel(const int* __restrict__ src,
                                 const int* __restrict__ dst, int E,
                                 int* __restrict__ fill, int* __restrict__ col,
                                 const float* __restrict__ dis,
                                 float* __restrict__ wnorm) {
    int e = blockIdx.x * blockDim.x + threadIdx.x;
    if (e < E) {
        int s = src[e];
        int d = dst[e];
        int pos = atomicAdd(&fill[d], 1);
        col[pos] = s;
        wnorm[pos] = dis[s] * dis[d];
    }
}

// ---------------------------------------------------------------------------
// MFMA bf16x3 (split-fp32) GEMM (round-8 proven): C = bf16(A[M,256] @ B[256,N]).
// Natural register budget (~100 VGPR); forcing occupancy spills (round-11).
// ---------------------------------------------------------------------------

template <int NCOLS>
__global__ __launch_bounds__(256) void gemm_mfma_kernel(const float* __restrict__ A,
                                                        const float* __restrict__ B,
                                                        unsigned short* __restrict__ C,
                                                        int M) {
    __shared__ unsigned short lds[4 * 128 * 40];
    const int t = threadIdx.x;
    const int ntn = NCOLS / 128;
    const int tile = blockIdx.x;
    unsigned short(*As_hi)[40] = (unsigned short(*)[40])(lds);
    unsigned short(*As_lo)[40] = (unsigned short(*)[40])(lds + 128 * 40);
    unsigned short(*Bs_hi)[40] = (unsigned short(*)[40])(lds + 2 * 128 * 40);
    unsigned short(*Bs_lo)[40] = (unsigned short(*)[40])(lds + 3 * 128 * 40);

    const int lane = t & 63;
    const int wid = t >> 6;
    const int wm = wid >> 1;
    const int wn = wid & 1;
    const int m0 = (tile / ntn) * 128;
    const int n0 = (tile % ntn) * 128;

    const int a_r = t >> 3;
    const int a_c4 = t & 7;
    const int b_col = t & 127;
    const int b_kq0 = t >> 7;

    f32x4 acc[4][4];
#pragma unroll
    for (int i = 0; i < 4; ++i)
#pragma unroll
        for (int j = 0; j < 4; ++j) acc[i][j] = (f32x4)(0.f);

    for (int k0 = 0; k0 < K_DIM; k0 += 32) {
        __syncthreads();
#pragma unroll
        for (int p = 0; p < 4; ++p) {
            const int row = a_r + p * 32;
            const int grow = min(m0 + row, M - 1);
            const float4 v = *(const float4*)(A + (size_t)grow * K_DIM + k0 + a_c4 * 4);
            unsigned short h0 = bf16_hi(v.x), h1 = bf16_hi(v.y),
                           h2 = bf16_hi(v.z), h3 = bf16_hi(v.w);
            unsigned short l0 = bf16_hi(v.x - bf16_back(h0)),
                           l1 = bf16_hi(v.y - bf16_back(h1)),
                           l2 = bf16_hi(v.z - bf16_back(h2)),
                           l3 = bf16_hi(v.w - bf16_back(h3));
            *(ushort4*)&As_hi[row][a_c4 * 4] = make_ushort4(h0, h1, h2, h3);
            *(ushort4*)&As_lo[row][a_c4 * 4] = make_ushort4(l0, l1, l2, l3);
        }
#pragma unroll
        for (int p = 0; p < 4; ++p) {
            const int kq = b_kq0 + p * 2;
            float v0 = B[(size_t)(k0 + kq * 4 + 0) * NCOLS + n0 + b_col];
            float v1 = B[(size_t)(k0 + kq * 4 + 1) * NCOLS + n0 + b_col];
            float v2 = B[(size_t)(k0 + kq * 4 + 2) * NCOLS + n0 + b_col];
            float v3 = B[(size_t)(k0 + kq * 4 + 3) * NCOLS + n0 + b_col];
            unsigned short h0 = bf16_hi(v0), h1 = bf16_hi(v1),
                           h2 = bf16_hi(v2), h3 = bf16_hi(v3);
            unsigned short l0 = bf16_hi(v0 - bf16_back(h0)),
                           l1 = bf16_hi(v1 - bf16_back(h1)),
                           l2 = bf16_hi(v2 - bf16_back(h2)),
                           l3 = bf16_hi(v3 - bf16_back(h3));
            *(ushort4*)&Bs_hi[b_col][kq * 4] = make_ushort4(h0, h1, h2, h3);
            *(ushort4*)&Bs_lo[b_col][kq * 4] = make_ushort4(l0, l1, l2, l3);
        }
        __syncthreads();

        const int fr = lane & 15;
        const int fk = (lane >> 4) * 8;
        short8 a_hi[4], a_lo[4], b_hi[4], b_lo[4];
#pragma unroll
        for (int fm = 0; fm < 4; ++fm) {
            const int r = wm * 64 + fm * 16 + fr;
            a_hi[fm] = *(const short8*)&As_hi[r][fk];
            a_lo[fm] = *(const short8*)&As_lo[r][fk];
        }
#pragma unroll
        for (int fn = 0; fn < 4; ++fn) {
            const int c = wn * 64 + fn * 16 + fr;
            b_hi[fn] = *(const short8*)&Bs_hi[c][fk];
            b_lo[fn] = *(const short8*)&Bs_lo[c][fk];
        }
#pragma unroll
        for (int fm = 0; fm < 4; ++fm)
#pragma unroll
            for (int fn = 0; fn < 4; ++fn) {
                acc[fm][fn] = __builtin_amdgcn_mfma_f32_16x16x32_bf16(
                    a_hi[fm], b_hi[fn], acc[fm][fn], 0, 0, 0);
                acc[fm][fn] = __builtin_amdgcn_mfma_f32_16x16x32_bf16(
                    a_hi[fm], b_lo[fn], acc[fm][fn], 0, 0, 0);
                acc[fm][fn] = __builtin_amdgcn_mfma_f32_16x16x32_bf16(
                    a_lo[fm], b_hi[fn], acc[fm][fn], 0, 0, 0);
            }
    }

    const int c_col = n0 + wn * 64 + (lane & 15);
    const int r_base = m0 + wm * 64 + (lane >> 4) * 4;
#pragma unroll
    for (int fm = 0; fm < 4; ++fm)
#pragma unroll
        for (int fn = 0; fn < 4; ++fn)
#pragma unroll
            for (int r = 0; r < 4; ++r) {
                const int row = r_base + fm * 16 + r;
                if (row < M)
                    C[(size_t)row * NCOLS + c_col + fn * 16] = bf16_hi(acc[fm][fn][r]);
            }
}

// ---------------------------------------------------------------------------
// CSR aggregation over bf16 features; edge loop unrolled x4 (latency-bound
// gather, VALUBusy ~29% -> more outstanding loads per wave).
// ---------------------------------------------------------------------------

template <int F, bool RELU>
__global__ __launch_bounds__(256) void aggregate_kernel(
    const unsigned short* __restrict__ xw, const int* __restrict__ row_ptr,
    const int* __restrict__ col, const float* __restrict__ wnorm,
    const float* __restrict__ dis, const float* __restrict__ bias,
    float* __restrict__ out, int N) {
    constexpr int VEC = F / 64;
    const int wid = threadIdx.x >> 6;
    const int lane = threadIdx.x & 63;
    const int n = blockIdx.x * 4 + wid;
    if (n >= N) return;

    const float dn = dis[n];
    float acc[VEC];
    {
        const float w = dn * dn;
        const unsigned short* xn = xw + (size_t)n * F + lane * VEC;
        if (VEC == 4) {
            const ushort4 u = *(const ushort4*)xn;
            acc[0] = bf2f(u.x) * w;
            acc[1] = bf2f(u.y) * w;
            acc[2] = bf2f(u.z) * w;
            acc[3] = bf2f(u.w) * w;
        } else {
            const ushort2 u = *(const ushort2*)xn;
            acc[0] = bf2f(u.x) * w;
            acc[1] = bf2f(u.y) * w;
        }
    }

    const int e0 = row_ptr[n];
    const int e1 = row_ptr[n + 1];
    int e = e0;
    for (; e + 4 <= e1; e += 4) {
        const int s0 = col[e], s1 = col[e + 1], s2 = col[e + 2], s3 = col[e + 3];
        const float w0 = wnorm[e], w1 = wnorm[e + 1], w2 = wnorm[e + 2], w3 = wnorm[e + 3];
        const unsigned short* x0 = xw + (size_t)s0 * F + lane * VEC;
        const unsigned short* x1 = xw + (size_t)s1 * F + lane * VEC;
        const unsigned short* x2 = xw + (size_t)s2 * F + lane * VEC;
        const unsigned short* x3 = xw + (size_t)s3 * F + lane * VEC;
        if (VEC == 4) {
            const ushort4 u0 = *(const ushort4*)x0;
            const ushort4 u1 = *(const ushort4*)x1;
            const ushort4 u2 = *(const ushort4*)x2;
            const ushort4 u3 = *(const ushort4*)x3;
            acc[0] += bf2f(u0.x) * w0 + bf2f(u1.x) * w1 + bf2f(u2.x) * w2 + bf2f(u3.x) * w3;
            acc[1] += bf2f(u0.y) * w0 + bf2f(u1.y) * w1 + bf2f(u2.y) * w2 + bf2f(u3.y) * w3;
            acc[2] += bf2f(u0.z) * w0 + bf2f(u1.z) * w1 + bf2f(u2.z) * w2 + bf2f(u3.z) * w3;
            acc[3] += bf2f(u0.w) * w0 + bf2f(u1.w) * w1 + bf2f(u2.w) * w2 + bf2f(u3.w) * w3;
        } else {
            const ushort2 u0 = *(const ushort2*)x0;
            const ushort2 u1 = *(const ushort2*)x1;
            const ushort2 u2 = *(const ushort2*)x2;
            const ushort2 u3 = *(const ushort2*)x3;
            acc[0] += bf2f(u0.x) * w0 + bf2f(u1.x) * w1 + bf2f(u2.x) * w2 + bf2f(u3.x) * w3;
            acc[1] += bf2f(u0.y) * w0 + bf2f(u1.y) * w1 + bf2f(u2.y) * w2 + bf2f(u3.y) * w3;
        }
    }
    for (; e < e1; ++e) {
        const int s0 = col[e];
        const float w0 = wnorm[e];
        const unsigned short* x0 = xw + (size_t)s0 * F + lane * VEC;
        if (VEC == 4) {
            const ushort4 u0 = *(const ushort4*)x0;
            acc[0] += bf2f(u0.x) * w0;
            acc[1] += bf2f(u0.y) * w0;
            acc[2] += bf2f(u0.z) * w0;
            acc[3] += bf2f(u0.w) * w0;
        } else {
            const ushort2 u0 = *(const ushort2*)x0;
            acc[0] += bf2f(u0.x) * w0;
            acc[1] += bf2f(u0.y) * w0;
        }
    }

    float* o = out + (size_t)n * F + lane * VEC;
#pragma unroll
    for (int v = 0; v < VEC; ++v) {
        float r = acc[v] + bias[lane * VEC + v];
        if (RELU) r = fmaxf(r, 0.f);
        o[v] = r;
    }
}

// ---------------------------------------------------------------------------
// Launch: 9 dispatches, single stream, no cooperative launch.
// ---------------------------------------------------------------------------

extern "C" void kernel_launch(void* const* d_in, const int* in_sizes, int n_in,
                              void* d_out, int out_size, void* d_ws, size_t ws_size,
                              hipStream_t stream) {
    const float* x = (const float*)d_in[0];
    const int* edge = (const int*)d_in[1];
    const float* W1 = (const float*)d_in[2];
    const float* b1 = (const float*)d_in[3];
    const float* W2 = (const float*)d_in[4];
    const float* b2 = (const float*)d_in[5];

    const int N = in_sizes[0] / 256;   // 50000
    const int E = in_sizes[1] / 2;     // 800000
    const int* src = edge;
    const int* dst = edge + E;

    char* w = (char*)d_ws;
    auto carve = [&](size_t bytes) {
        char* p = w;
        w += (bytes + 255) & ~(size_t)255;
        return p;
    };
    const int nscan = (N + SCAN_C - 1) / SCAN_C;   // 98
    int* cnt = (int*)carve((size_t)N * 4);
    int* row_ptr = (int*)carve((size_t)(N + 1) * 4);
    int* fill = (int*)carve((size_t)N * 4);
    int* col = (int*)carve((size_t)E * 4);
    float* wnorm = (float*)carve((size_t)E * 4);
    float* dis = (float*)carve((size_t)N * 4);
    int* bsum = (int*)carve((size_t)nscan * 4);
    unsigned short* xw1 = (unsigned short*)carve((size_t)N * 256 * 2);  // bf16
    float* h = (float*)carve((size_t)N * 256 * 4);                      // fp32
    unsigned short* xw2 = xw1;  // alias: xw1 dead after aggregate1

    float* out = (float*)d_out;

    hipMemsetAsync(cnt, 0, (size_t)N * 4, stream);
    const int eblocks = (E + 255) / 256;
    degree_hist_kernel<<<eblocks, 256, 0, stream>>>(dst, E, cnt);
    scan_phase1<<<nscan, 256, 0, stream>>>(cnt, bsum, N);
    scan_phase23<<<nscan, 256, 0, stream>>>(cnt, bsum, nscan, row_ptr, fill, dis, N);
    build_csr_kernel<<<eblocks, 256, 0, stream>>>(src, dst, E, fill, col, dis, wnorm);

    // layer 1: xw1 = bf16(x @ W1) ; h = agg(xw1)+b1, ReLU
    {
        dim3 grid(2 * ((N + 127) / 128));
        gemm_mfma_kernel<256><<<grid, 256, 0, stream>>>(x, W1, xw1, N);
    }
    aggregate_kernel<256, true><<<(N + 3) / 4, 256, 0, stream>>>(
        xw1, row_ptr, col, wnorm, dis, b1, h, N);

    // layer 2: xw2 = bf16(h @ W2) ; out = agg(xw2)+b2
    {
        dim3 grid((N + 127) / 128);
        gemm_mfma_kernel<128><<<grid, 256, 0, stream>>>(h, W2, xw2, N);
    }
    aggregate_kernel<128, false><<<(N + 3) / 4, 256, 0, stream>>>(
        xw2, row_ptr, col, wnorm, dis, b2, out, N);
}